// Round 5
// baseline (79.427 us; speedup 1.0000x reference)
//
#include <hip/hip_runtime.h>

// MaxPoolFaceFeature: out[m,c,f] = max(fea[m,c,f], max_k fea[m,c,ring_n[m,f,k]])
// fea: [M=8, C=256, F=20000] f32, ring: [M=8, F=20000, K=3] i32.
//
// R5: one block per (m, channel-PAIR). Both rows interleaved in LDS as
// float2 {A[f], B[f]} (160000 B = full CU LDS, 1 block/CU, 16 waves).
//  - ds_read_b64 gather returns BOTH channels -> gather instrs/channel halve.
//  - ring indices read once per pair (register prefetch, 15 int4/thread)
//    BEFORE the staging barrier -> ring L2 latency hides under staging HBM.
//  - own values re-read from LDS as 2x b128 (contains both channels).
// R4 post-mortem: all pipes ~50% busy; per-channel duplicated ring/gather
// work was the cost, not occupancy.

#define NM 8
#define NC 256
#define NF 20000
#define BT 1024
#define NQ (NF / 4)            // 5000 float4-quads per row
#define FULLP 4                // 4*1024 = 4096 full passes
#define TAILN (NQ - FULLP*BT)  // 904

__global__ __launch_bounds__(BT) void mpff_kernel(
    const float* __restrict__ fea,
    const int*   __restrict__ ring,
    float*       __restrict__ out)
{
    extern __shared__ float2 lds2[];   // [NF] {chA, chB} per face

    const int m  = blockIdx.x & 7;     // mesh -> XCD affinity
    const int cp = blockIdx.x >> 3;    // channel pair 0..127

    const long baseA = ((long)m * NC + cp * 2) * NF;
    const float4* srcA = (const float4*)(fea + baseA);
    const float4* srcB = (const float4*)(fea + baseA + NF);
    float4*       dstA = (float4*)(out + baseA);
    float4*       dstB = (float4*)(out + baseA + NF);

    const int4* ring4 = (const int4*)(ring + (long)m * NF * 3);
    const int tid = threadIdx.x;

    // ---- 1) ring prefetch into registers (concurrent with staging loads) ----
    int4 rg0[FULLP], rg1[FULLP], rg2[FULLP];
    #pragma unroll
    for (int p = 0; p < FULLP; ++p) {
        const int q = tid + p * BT;
        rg0[p] = ring4[q * 3 + 0];
        rg1[p] = ring4[q * 3 + 1];
        rg2[p] = ring4[q * 3 + 2];
    }
    int4 tg0, tg1, tg2;
    if (tid < TAILN) {
        const int q = tid + FULLP * BT;
        tg0 = ring4[q * 3 + 0];
        tg1 = ring4[q * 3 + 1];
        tg2 = ring4[q * 3 + 2];
    }

    // ---- 2) stage both rows, interleaved, into LDS ----
    #pragma unroll
    for (int p = 0; p < FULLP; ++p) {
        const int q = tid + p * BT;
        const float4 a = srcA[q];
        const float4 b = srcB[q];
        float4* w = (float4*)&lds2[q * 4];
        w[0] = make_float4(a.x, b.x, a.y, b.y);
        w[1] = make_float4(a.z, b.z, a.w, b.w);
    }
    if (tid < TAILN) {
        const int q = tid + FULLP * BT;
        const float4 a = srcA[q];
        const float4 b = srcB[q];
        float4* w = (float4*)&lds2[q * 4];
        w[0] = make_float4(a.x, b.x, a.y, b.y);
        w[1] = make_float4(a.z, b.z, a.w, b.w);
    }
    __syncthreads();

    // ---- 3) gather (b64 = both channels) + max + store ----
    #define PROCESS(q, ra, rb, rc)                                            \
    {                                                                         \
        const float4* vr = (const float4*)&lds2[(q) * 4];                     \
        const float4 v0 = vr[0]; /* A0 B0 A1 B1 */                            \
        const float4 v1 = vr[1]; /* A2 B2 A3 B3 */                            \
        const float2 n00 = lds2[(ra).x], n01 = lds2[(ra).y], n02 = lds2[(ra).z];\
        const float2 n10 = lds2[(ra).w], n11 = lds2[(rb).x], n12 = lds2[(rb).y];\
        const float2 n20 = lds2[(rb).z], n21 = lds2[(rb).w], n22 = lds2[(rc).x];\
        const float2 n30 = lds2[(rc).y], n31 = lds2[(rc).z], n32 = lds2[(rc).w];\
        float4 oA, oB;                                                        \
        oA.x = fmaxf(fmaxf(v0.x, n00.x), fmaxf(n01.x, n02.x));                \
        oB.x = fmaxf(fmaxf(v0.y, n00.y), fmaxf(n01.y, n02.y));                \
        oA.y = fmaxf(fmaxf(v0.z, n10.x), fmaxf(n11.x, n12.x));                \
        oB.y = fmaxf(fmaxf(v0.w, n10.y), fmaxf(n11.y, n12.y));                \
        oA.z = fmaxf(fmaxf(v1.x, n20.x), fmaxf(n21.x, n22.x));                \
        oB.z = fmaxf(fmaxf(v1.y, n20.y), fmaxf(n21.y, n22.y));                \
        oA.w = fmaxf(fmaxf(v1.z, n30.x), fmaxf(n31.x, n32.x));                \
        oB.w = fmaxf(fmaxf(v1.w, n30.y), fmaxf(n31.y, n32.y));                \
        dstA[(q)] = oA;                                                       \
        dstB[(q)] = oB;                                                       \
    }

    #pragma unroll
    for (int p = 0; p < FULLP; ++p) {
        const int q = tid + p * BT;
        PROCESS(q, rg0[p], rg1[p], rg2[p]);
    }
    if (tid < TAILN) {
        const int q = tid + FULLP * BT;
        PROCESS(q, tg0, tg1, tg2);
    }
    #undef PROCESS
}

extern "C" void kernel_launch(void* const* d_in, const int* in_sizes, int n_in,
                              void* d_out, int out_size, void* d_ws, size_t ws_size,
                              hipStream_t stream) {
    const float* fea  = (const float*)d_in[0];
    const int*   ring = (const int*)d_in[1];
    float*       out  = (float*)d_out;

    hipFuncSetAttribute((const void*)mpff_kernel,
                        hipFuncAttributeMaxDynamicSharedMemorySize, NF * 8);

    // 8 meshes x 128 channel pairs; m = blockIdx & 7 (1024 % 8 == 0, bijective).
    mpff_kernel<<<NM * (NC / 2), BT, NF * 8, stream>>>(fea, ring, out);
}

// Round 7
// 54.794 us; speedup vs baseline: 1.4496x; 1.4496x over previous
//
#include <hip/hip_runtime.h>

// MaxPoolFaceFeature: out[m,c,f] = max(fea[m,c,f], max_k fea[m,c,ring_n[m,f,k]])
// fea: [M=8, C=256, F=20000] f32, ring: [M=8, F=20000, K=3] i32.
//
// R7 = R6 with the compile fix: __builtin_nontemporal_store requires a
// native clang vector type, not HIP's float4 class -> use ext_vector_type.
//  - staging via __builtin_amdgcn_global_load_lds width=16 (no VGPR trip).
//  - nontemporal float4 stores for out (write-once; don't evict fea).
//  - ring passes 0-1 prefetched between stage-issue and barrier.
//  - 80 KB/block (one channel), 1024 thr, 2 blocks/CU.

#define NM 8
#define NC 256
#define NF 20000
#define BT 1024
#define NQ (NF / 4)            // 5000 float4 per row
#define FULLP 4                // 4*1024 = 4096 full passes
#define TAILN (NQ - FULLP*BT)  // 904

typedef const __attribute__((address_space(1))) void* gas_ptr;
typedef __attribute__((address_space(3))) void* las_ptr;
typedef float vfloat4 __attribute__((ext_vector_type(4)));

__device__ __forceinline__ vfloat4 mp4(const float* __restrict__ row,
                                       const vfloat4 v,
                                       const int4 ra, const int4 rb, const int4 rc)
{
    vfloat4 o;
    o.x = fmaxf(fmaxf(v.x, row[ra.x]), fmaxf(row[ra.y], row[ra.z]));
    o.y = fmaxf(fmaxf(v.y, row[ra.w]), fmaxf(row[rb.x], row[rb.y]));
    o.z = fmaxf(fmaxf(v.z, row[rb.z]), fmaxf(row[rb.w], row[rc.x]));
    o.w = fmaxf(fmaxf(v.w, row[rc.y]), fmaxf(row[rc.z], row[rc.w]));
    return o;
}

__global__ __launch_bounds__(BT) void mpff_kernel(
    const float* __restrict__ fea,
    const int*   __restrict__ ring,
    float*       __restrict__ out)
{
    extern __shared__ float row[];   // NF floats = 80000 B
    vfloat4* row4 = (vfloat4*)row;

    const int m = blockIdx.x & 7;    // mesh -> XCD affinity
    const int c = blockIdx.x >> 3;   // channel

    const long base = ((long)m * NC + c) * NF;
    const vfloat4* src4 = (const vfloat4*)(fea + base);
    vfloat4*       dst4 = (vfloat4*)(out + base);
    const int4*    ring4 = (const int4*)(ring + (long)m * NF * 3);

    const int tid   = threadIdx.x;
    const int wbase = tid & ~63;     // wave-uniform LDS base (lane x 16B applied by HW)

    // ---- 1) async stage HBM->LDS, 4 full passes, no register round trip ----
    #pragma unroll
    for (int p = 0; p < FULLP; ++p) {
        const int q = tid + p * BT;
        __builtin_amdgcn_global_load_lds((gas_ptr)(src4 + q),
                                         (las_ptr)(row4 + wbase + p * BT),
                                         16, 0, 0);
    }
    // tail (904 quads, partial wave) through registers
    if (tid < TAILN) {
        const int q = tid + FULLP * BT;
        row4[q] = src4[q];
    }

    // ---- 2) ring prefetch passes 0-1: flies during the staging drain ----
    const int4 a0 = ring4[tid * 3 + 0];
    const int4 b0 = ring4[tid * 3 + 1];
    const int4 c0 = ring4[tid * 3 + 2];
    const int4 a1 = ring4[(tid + BT) * 3 + 0];
    const int4 b1 = ring4[(tid + BT) * 3 + 1];
    const int4 c1 = ring4[(tid + BT) * 3 + 2];

    __syncthreads();

    // ---- 3) gather + max + nt-store ----
    {   // passes 0,1 (prefetched indices)
        const int q0 = tid, q1 = tid + BT;
        const vfloat4 v0 = row4[q0];
        const vfloat4 v1 = row4[q1];
        __builtin_nontemporal_store(mp4(row, v0, a0, b0, c0), &dst4[q0]);
        __builtin_nontemporal_store(mp4(row, v1, a1, b1, c1), &dst4[q1]);
    }
    {   // passes 2,3
        const int q0 = tid + 2 * BT, q1 = tid + 3 * BT;
        const int4 a2 = ring4[q0 * 3 + 0], b2 = ring4[q0 * 3 + 1], c2 = ring4[q0 * 3 + 2];
        const int4 a3 = ring4[q1 * 3 + 0], b3 = ring4[q1 * 3 + 1], c3 = ring4[q1 * 3 + 2];
        const vfloat4 v0 = row4[q0];
        const vfloat4 v1 = row4[q1];
        __builtin_nontemporal_store(mp4(row, v0, a2, b2, c2), &dst4[q0]);
        __builtin_nontemporal_store(mp4(row, v1, a3, b3, c3), &dst4[q1]);
    }
    if (tid < TAILN) {  // tail pass
        const int q = tid + FULLP * BT;
        const int4 a = ring4[q * 3 + 0], b = ring4[q * 3 + 1], cc = ring4[q * 3 + 2];
        const vfloat4 v = row4[q];
        __builtin_nontemporal_store(mp4(row, v, a, b, cc), &dst4[q]);
    }
}

extern "C" void kernel_launch(void* const* d_in, const int* in_sizes, int n_in,
                              void* d_out, int out_size, void* d_ws, size_t ws_size,
                              hipStream_t stream) {
    const float* fea  = (const float*)d_in[0];
    const int*   ring = (const int*)d_in[1];
    float*       out  = (float*)d_out;

    (void)hipFuncSetAttribute((const void*)mpff_kernel,
                              hipFuncAttributeMaxDynamicSharedMemorySize, NF * 4);

    // 8 meshes x 256 channels; m = blockIdx & 7 (2048 % 8 == 0, bijective).
    mpff_kernel<<<NM * NC, BT, NF * 4, stream>>>(fea, ring, out);
}